// Round 4
// baseline (374.676 us; speedup 1.0000x reference)
//
#include <hip/hip_runtime.h>

// ---- output layout (floats) ----
#define LOSS_OFF  8388608
#define IDX_OFF   8388609
#define NCS_OFF   8454145
#define EMAW_OFF  8454657
#define EMB_OFF   8520193

__device__ __forceinline__ float rdl(float v, int l) {
  return __int_as_float(__builtin_amdgcn_readlane(__float_as_int(v), l));
}

// ||e_k||^2 precompute
__global__ __launch_bounds__(256) void ee_kernel(const float* __restrict__ emb,
                                                 float* __restrict__ ee) {
  int lane = threadIdx.x & 63;
  int wave = threadIdx.x >> 6;
  int kbase = (blockIdx.x * 4 + wave) * 16;
  for (int i = 0; i < 16; ++i) {
    int k = kbase + i;
    float2 v = *(const float2*)(emb + (size_t)k * 128 + lane * 2);
    float p = v.x * v.x + v.y * v.y;
    #pragma unroll
    for (int o = 32; o; o >>= 1) p += __shfl_xor(p, o);
    if (lane == 0) ee[k] = p;
  }
}

// distances + argmin + fused-entropy softmax + quantized gather.
// K in 2 halves of 256; lane owns k = 256h + 4*lane + j. acc[8][4] = 32 VGPRs.
// Cross-half softmax state lives in LDS (wave-uniform scalars), not registers.
// waves_per_eu(2,4): cap occupancy at 4 waves/EU so RA may use up to 128 VGPRs.
__global__ __attribute__((amdgpu_flat_work_group_size(256, 256),
                          amdgpu_waves_per_eu(2, 4)))
void dist_kernel(
    const float* __restrict__ inputs, const float* __restrict__ emb,
    const float* __restrict__ ee, float* __restrict__ out,
    float* __restrict__ idxws, float* __restrict__ sums)
{
  __shared__ float smem[32 * 292];   // es (37.4 KB); xs/eq alias front [32][132]
  __shared__ float red[8];
  __shared__ float sM[32], sS[32], sT[32];
  __shared__ int   ibk[32];
  float* es = smem;
  float* xs = smem;

  const int t = threadIdx.x, lane = t & 63, wave = t >> 6;
  const int n0 = blockIdx.x * 32;
  const int b = n0 >> 15, s0 = n0 & 32767;

  // stage x tile [row][c]
  {
    const int r = t & 31, c0 = (t >> 5) * 16;
    const float* src = inputs + (size_t)b * 128 * 32768 + s0 + r;
    #pragma unroll
    for (int i = 0; i < 16; ++i)
      xs[r * 132 + c0 + i] = src[(size_t)(c0 + i) * 32768];
  }
  __syncthreads();

  // xv[2r+h] at lane m == x[row r][h*64+m]
  float xv[16];
  #pragma unroll
  for (int r = 0; r < 8; ++r) {
    xv[2*r]   = xs[(wave*8 + r) * 132 + lane];
    xv[2*r+1] = xs[(wave*8 + r) * 132 + 64 + lane];
  }

  const int lofs = 4 * lane + 4 * (lane >> 3);
  float commit_acc = 0.f, ent_acc = 0.f;

  #pragma unroll 1
  for (int h = 0; h < 2; ++h) {
    float acc[8][4];
    #pragma unroll
    for (int r = 0; r < 8; ++r)
      #pragma unroll
      for (int j = 0; j < 4; ++j) acc[r][j] = 0.f;

    for (int cc = 0; cc < 4; ++cc) {
      __syncthreads();
      // stage 256 k x 32 c: granule (k = g>>3, m = g&7); comp u -> col m+8u
      #pragma unroll
      for (int i = 0; i < 8; ++i) {
        int g = t + 256 * i;
        int k = g >> 3, m = g & 7;
        int kpos = k + 4 * (k >> 5);
        float4 v = *(const float4*)(emb + (size_t)(h * 256 + k) * 128 + cc * 32 + m * 4);
        es[(m +  0) * 292 + kpos] = v.x;
        es[(m +  8) * 292 + kpos] = v.y;
        es[(m + 16) * 292 + kpos] = v.z;
        es[(m + 24) * 292 + kpos] = v.w;
      }
      __syncthreads();
      const int hc = cc >> 1;               // which 64-c half of xv
      const int lbase = (cc & 1) * 32;
      #pragma unroll 4
      for (int pc = 0; pc < 32; ++pc) {
        float4 e4 = *(const float4*)&es[pc * 292 + lofs];
        const int li = lbase + 4 * (pc & 7) + (pc >> 3);
        #pragma unroll
        for (int r = 0; r < 8; ++r) {
          float sx = rdl(xv[2*r + hc], li);
          acc[r][0] += sx * e4.x; acc[r][1] += sx * e4.y;
          acc[r][2] += sx * e4.z; acc[r][3] += sx * e4.w;
        }
      }
    }

    // epilogue half h (distances shifted by -||x||^2: argmin/softmax invariant)
    float4 ee4 = *(const float4*)(ee + h * 256 + 4 * lane);
    #pragma unroll
    for (int r = 0; r < 8; ++r) {
      const int row = wave * 8 + r;
      float dd[4];
      dd[0] = ee4.x - 2.f * acc[r][0];
      dd[1] = ee4.y - 2.f * acc[r][1];
      dd[2] = ee4.z - 2.f * acc[r][2];
      dd[3] = ee4.w - 2.f * acc[r][3];
      float ml = dd[0]; int jb = 0;
      #pragma unroll
      for (int j = 1; j < 4; ++j) if (dd[j] < ml) { ml = dd[j]; jb = j; }
      int bkl = h * 256 + 4 * lane + jb;
      #pragma unroll
      for (int o = 32; o; o >>= 1) {
        float om = __shfl_xor(ml, o); int ob = __shfl_xor(bkl, o);
        if (om < ml || (om == ml && ob < bkl)) { ml = om; bkl = ob; }
      }
      float sl = 0.f, tl = 0.f;
      #pragma unroll
      for (int j = 0; j < 4; ++j) {
        float z = ml - dd[j];
        float e = __expf(z);
        sl += e; tl += z * e;
      }
      #pragma unroll
      for (int o = 32; o; o >>= 1) { sl += __shfl_xor(sl, o); tl += __shfl_xor(tl, o); }

      if (h == 0) {
        if (lane == 0) { sM[row] = ml; sS[row] = sl; sT[row] = tl; ibk[row] = bkl; }
      } else {
        // merge with half-0 state (broadcast LDS reads; values wave-uniform)
        float mo = sM[row], So = sS[row], To = sT[row];
        int   bo = ibk[row];
        float mM, SM, TM; int bM;
        if (ml < mo) {
          float f = __expf(ml - mo);
          SM = sl + So * f;
          TM = tl + (To + (ml - mo) * So) * f;
          mM = ml; bM = bkl;
        } else {                             // ties keep half-0 (smaller) index
          float f = __expf(mo - ml);
          SM = So + sl * f;
          TM = To + (tl + (mo - ml) * sl) * f;
          mM = mo; bM = bo;
        }
        // ||x_row||^2
        float p = xv[2*r] * xv[2*r] + xv[2*r+1] * xv[2*r+1];
        #pragma unroll
        for (int o = 32; o; o >>= 1) p += __shfl_xor(p, o);
        if (lane == 0) {
          int rn = n0 + row;
          out[IDX_OFF + rn] = (float)bM;
          idxws[rn] = (float)bM;
          ibk[row] = bM;
          commit_acc += p + mM;              // d_min = ||x||^2 + shifted-min
          ent_acc    += TM / SM - __logf(SM);
        }
      }
    }
  }

  if (lane == 0) { red[wave] = commit_acc; red[4 + wave] = ent_acc; }
  __syncthreads();
  if (t == 0) {
    unsafeAtomicAdd(&sums[0], red[0] + red[1] + red[2] + red[3]);
    unsafeAtomicAdd(&sums[1], red[4] + red[5] + red[6] + red[7]);
  }

  // fused gather: eq[r][c] = emb[bk_r][c] (reuse smem as [32][132])
  {
    const int r = t & 31, c0 = (t >> 5) * 16;
    const int kq = ibk[r];
    const float* src = emb + (size_t)kq * 128 + c0;
    float4 v0 = *(const float4*)(src);
    float4 v1 = *(const float4*)(src + 4);
    float4 v2 = *(const float4*)(src + 8);
    float4 v3 = *(const float4*)(src + 12);
    float* dst = &xs[r * 132 + c0];
    *(float4*)(dst) = v0; *(float4*)(dst+4) = v1;
    *(float4*)(dst+8) = v2; *(float4*)(dst+12) = v3;
  }
  __syncthreads();
  {
    const int l7 = t & 7;
    #pragma unroll
    for (int pp = 0; pp < 4; ++pp) {
      int c = (t >> 3) + 32 * pp;
      float4 v;
      v.x = xs[(4*l7 + 0) * 132 + c];
      v.y = xs[(4*l7 + 1) * 132 + c];
      v.z = xs[(4*l7 + 2) * 132 + c];
      v.w = xs[(4*l7 + 3) * 132 + c];
      *(float4*)(out + ((size_t)b * 128 + c) * 32768 + s0 + 4 * l7) = v;
    }
  }
}

// dw scatter: block = (row-split s, 8-channel slice ccB), grid = 16*S
__global__ __launch_bounds__(256) void scatter_kernel(
    const float* __restrict__ inputs, const float* __restrict__ idxws,
    float* __restrict__ partial, float* __restrict__ cpart, int S)
{
  __shared__ float acc[512 * 9];
  __shared__ float cnts[512];
  const int t = threadIdx.x;
  const int s = blockIdx.x >> 4, ccB = blockIdx.x & 15;
  const int R = 65536 / S;
  for (int m = t; m < 512 * 9; m += 256) acc[m] = 0.f;
  if (ccB == 0) for (int m = t; m < 512; m += 256) cnts[m] = 0.f;
  __syncthreads();
  const int l = t & 63, cg = t >> 6;
  for (int it = 0; it < R / 256; ++it) {
    int n = s * R + it * 256;
    int bb = n >> 15;
    int sp = (n & 32767) + 4 * l;
    float4 i4 = *(const float4*)(idxws + n + 4 * l);
    int k0 = (int)i4.x, k1 = (int)i4.y, k2 = (int)i4.z, k3 = (int)i4.w;
    #pragma unroll
    for (int ci = 0; ci < 2; ++ci) {
      int c = cg * 2 + ci;
      float4 x4 = *(const float4*)(inputs + ((size_t)bb * 128 + ccB * 8 + c) * 32768 + sp);
      atomicAdd(&acc[k0 * 9 + c], x4.x);
      atomicAdd(&acc[k1 * 9 + c], x4.y);
      atomicAdd(&acc[k2 * 9 + c], x4.z);
      atomicAdd(&acc[k3 * 9 + c], x4.w);
    }
    if (ccB == 0 && cg == 0) {
      atomicAdd(&cnts[k0], 1.f); atomicAdd(&cnts[k1], 1.f);
      atomicAdd(&cnts[k2], 1.f); atomicAdd(&cnts[k3], 1.f);
    }
  }
  __syncthreads();
  for (int m = t; m < 512 * 8; m += 256) {
    int k = m >> 3, c = m & 7;
    partial[(size_t)s * 65536 + k * 128 + ccB * 8 + c] = acc[k * 9 + c];
  }
  if (ccB == 0) for (int m = t; m < 512; m += 256) cpart[s * 512 + m] = cnts[m];
}

// finalize scalars
__global__ __launch_bounds__(512) void c1_kernel(const float* __restrict__ ecs,
    const float* __restrict__ cpart, const float* __restrict__ sums,
    float* __restrict__ invs, float* __restrict__ out, int S)
{
  __shared__ float sred[512];
  int t = threadIdx.x;
  float cnt = 0.f;
  for (int s = 0; s < S; ++s) cnt += cpart[s * 512 + t];
  float cn = 0.99f * ecs[t] + 0.01f * cnt;
  out[NCS_OFF + t] = cn;
  sred[t] = cn;
  __syncthreads();
  for (int o = 256; o; o >>= 1) {
    if (t < o) sred[t] += sred[t + o];
    __syncthreads();
  }
  float ntot = sred[0];
  float sm = (cn + 1e-5f) / (ntot + 0.00512f) * ntot;
  invs[t] = 1.f / sm;
  if (t == 0)
    out[LOSS_OFF] = 0.25f * sums[0] / 8388608.f - 0.01f * sums[1] / 65536.f;
}

// EMA weight update + normalized embedding (reduces S partials)
__global__ __launch_bounds__(256) void c2_kernel(const float* __restrict__ emaw,
    const float* __restrict__ partial, const float* __restrict__ invs,
    float* __restrict__ out, int S)
{
  int i = blockIdx.x * 256 + threadIdx.x;
  float dwv = 0.f;
  for (int s = 0; s < S; ++s) dwv += partial[(size_t)s * 65536 + i];
  float val = 0.99f * emaw[i] + 0.01f * dwv;
  out[EMAW_OFF + i] = val;
  out[EMB_OFF + i] = val * invs[i >> 7];
}

extern "C" void kernel_launch(void* const* d_in, const int* in_sizes, int n_in,
                              void* d_out, int out_size, void* d_ws, size_t ws_size,
                              hipStream_t stream) {
  const float* inputs = (const float*)d_in[0];
  const float* emb    = (const float*)d_in[1];
  const float* ecs    = (const float*)d_in[2];
  const float* emaw   = (const float*)d_in[3];
  float* out = (float*)d_out;
  float* wsf = (float*)d_ws;
  (void)in_sizes; (void)n_in; (void)out_size;

  size_t wsfl = ws_size / 4;
  int S = 32;
  while (S > 1 && (size_t)S * 66048 + 66592 > wsfl) S >>= 1;

  float* partial = wsf;
  float* cpart   = partial + (size_t)S * 65536;
  float* idxws   = cpart + (size_t)S * 512;
  float* sums    = idxws + 65536;
  float* ee      = sums + 16;
  float* invs    = ee + 512;

  hipMemsetAsync(sums, 0, 16 * sizeof(float), stream);
  ee_kernel     <<<8,      256, 0, stream>>>(emb, ee);
  dist_kernel   <<<2048,   256, 0, stream>>>(inputs, emb, ee, out, idxws, sums);
  scatter_kernel<<<16 * S, 256, 0, stream>>>(inputs, idxws, partial, cpart, S);
  c1_kernel     <<<1,      512, 0, stream>>>(ecs, cpart, sums, invs, out, S);
  c2_kernel     <<<256,    256, 0, stream>>>(emaw, partial, invs, out, S);
}

// Round 5
// 213.789 us; speedup vs baseline: 1.7525x; 1.7525x over previous
//
#include <hip/hip_runtime.h>

// ---- output layout (floats) ----
#define LOSS_OFF  8388608
#define IDX_OFF   8388609
#define NCS_OFF   8454145
#define EMAW_OFF  8454657
#define EMB_OFF   8520193

typedef __attribute__((ext_vector_type(8))) short short8;
typedef __attribute__((ext_vector_type(4))) float f32x4;

__device__ __forceinline__ unsigned short bf16r(float x) {
  unsigned u = __float_as_uint(x);
  u += 0x7fff + ((u >> 16) & 1);
  return (unsigned short)(u >> 16);
}
__device__ __forceinline__ float bf16tof(unsigned short h) {
  return __uint_as_float(((unsigned)h) << 16);
}

// codebook prep: bf16 hi/lo split + ||e_k||^2 (fp32). grid 256 x 256 (2 codes/block)
__global__ __launch_bounds__(256) void prep_kernel(const float* __restrict__ emb,
    unsigned short* __restrict__ ehig, unsigned short* __restrict__ elog,
    float* __restrict__ eeg)
{
  __shared__ float r1[256];
  const int t = threadIdx.x;
  const int k = blockIdx.x * 2 + (t >> 7);
  const int c = t & 127;
  float x = emb[k * 128 + c];
  unsigned short hh = bf16r(x);
  ehig[k * 128 + c] = hh;
  elog[k * 128 + c] = bf16r(x - bf16tof(hh));
  r1[t] = x * x;
  __syncthreads();
  #pragma unroll
  for (int off = 64; off; off >>= 1) {
    if ((t & 127) < off) r1[t] += r1[t + off];
    __syncthreads();
  }
  if ((t & 127) == 0) eeg[k] = r1[t];
}

// distances via split-bf16 MFMA + argmin + fused-entropy softmax + gather.
// Block = 256 thr / 4 waves; wave owns 32 rows (2 x 16-row MFMA groups); 128 rows/block.
// dot = hi*hi + hi*lo + lo*hi accumulated fp32 (lo*lo dropped, ~5e-5).
// A-frag: A[m=lane&15][k=quad*8+j]; B-frag: B[n=lane&15][k=quad*8+j];
// C/D: col(code)=lane&15, row=(lane>>4)*4+reg.
__global__ __attribute__((amdgpu_flat_work_group_size(256, 256),
                          amdgpu_waves_per_eu(2, 4)))
void dist_kernel(const float* __restrict__ inputs, const float* __restrict__ emb,
                 const unsigned short* __restrict__ ehig,
                 const unsigned short* __restrict__ elog,
                 const float* __restrict__ eeg, float* __restrict__ out,
                 float* __restrict__ idxws, float* __restrict__ sums)
{
  __shared__ __align__(16) unsigned short esm[2][64 * 136]; // hi/lo code stage (34.8 KB)
  __shared__ float eeL[512];
  __shared__ float xxs[128];
  __shared__ int   ibkL[128];
  __shared__ float red[8];
  float* xs = (float*)&esm[0][0];            // [32][132] fp32, transient alias

  const int t = threadIdx.x, lane = t & 63, wave = t >> 6;
  const int n0 = blockIdx.x * 128;
  const int b = n0 >> 15, s0 = n0 & 32767;
  const int col = lane & 15, quad = lane >> 4;

  eeL[t] = eeg[t]; eeL[256 + t] = eeg[256 + t];

  short8 ahi[2][4], alo[2][4];
  // ---- x staging rounds: 32 rows/round; owning wave extracts frags + ||x||^2 ----
  for (int r4 = 0; r4 < 4; ++r4) {
    __syncthreads();
    {
      const int rr = t & 31, c0 = (t >> 5) * 16;
      const float* src = inputs + (size_t)b * 128 * 32768 + s0 + r4 * 32 + rr;
      #pragma unroll
      for (int i = 0; i < 16; ++i)
        xs[rr * 132 + c0 + i] = src[(size_t)(c0 + i) * 32768];
    }
    __syncthreads();
    if (wave == r4) {
      #pragma unroll
      for (int rg = 0; rg < 2; ++rg) {
        float xacc = 0.f;
        const float* xr = &xs[(rg * 16 + col) * 132 + quad * 8];
        #pragma unroll
        for (int q = 0; q < 4; ++q) {
          float v[8];
          *(float4*)&v[0] = *(const float4*)(xr + q * 32);
          *(float4*)&v[4] = *(const float4*)(xr + q * 32 + 4);
          short8 h8, l8;
          #pragma unroll
          for (int j = 0; j < 8; ++j) {
            unsigned short hh = bf16r(v[j]);
            h8[j] = (short)hh;
            l8[j] = (short)bf16r(v[j] - bf16tof(hh));
            xacc += v[j] * v[j];
          }
          ahi[rg][q] = h8; alo[rg][q] = l8;
        }
        xacc += __shfl_xor(xacc, 16);
        xacc += __shfl_xor(xacc, 32);
        if (lane < 16) xxs[wave * 32 + rg * 16 + lane] = xacc;
      }
    }
  }

  float mS[8], sS[8], tS[8]; int kS[8];      // [rg*4+reg] online state per column-class
  #pragma unroll
  for (int i = 0; i < 8; ++i) { mS[i] = 1e30f; sS[i] = 0.f; tS[i] = 0.f; kS[i] = 0; }

  // ---- main loop: 8 stages x 64 codes ----
  for (int st = 0; st < 8; ++st) {
    __syncthreads();
    {
      const int k = t >> 2, cB = (t & 3) * 32;
      const size_t go = (size_t)(st * 64 + k) * 128 + cB;
      const uint4* gh = (const uint4*)(ehig + go);
      const uint4* gl = (const uint4*)(elog + go);
      uint4* dh = (uint4*)&esm[0][k * 136 + cB];
      uint4* dl = (uint4*)&esm[1][k * 136 + cB];
      #pragma unroll
      for (int i = 0; i < 4; ++i) dh[i] = gh[i];
      #pragma unroll
      for (int i = 0; i < 4; ++i) dl[i] = gl[i];
    }
    __syncthreads();
    for (int kt = 0; kt < 4; ++kt) {
      f32x4 ac0 = {0.f, 0.f, 0.f, 0.f}, ac1 = {0.f, 0.f, 0.f, 0.f};
      const int boff = (kt * 16 + col) * 136 + quad * 8;
      #pragma unroll
      for (int q = 0; q < 4; ++q) {
        short8 bh = *(const short8*)&esm[0][boff + q * 32];
        short8 bl = *(const short8*)&esm[1][boff + q * 32];
        ac0 = __builtin_amdgcn_mfma_f32_16x16x32_bf16(alo[0][q], bh, ac0, 0, 0, 0);
        ac1 = __builtin_amdgcn_mfma_f32_16x16x32_bf16(alo[1][q], bh, ac1, 0, 0, 0);
        ac0 = __builtin_amdgcn_mfma_f32_16x16x32_bf16(ahi[0][q], bl, ac0, 0, 0, 0);
        ac1 = __builtin_amdgcn_mfma_f32_16x16x32_bf16(ahi[1][q], bl, ac1, 0, 0, 0);
        ac0 = __builtin_amdgcn_mfma_f32_16x16x32_bf16(ahi[0][q], bh, ac0, 0, 0, 0);
        ac1 = __builtin_amdgcn_mfma_f32_16x16x32_bf16(ahi[1][q], bh, ac1, 0, 0, 0);
      }
      const int code = st * 64 + kt * 16 + col;
      const float eec = eeL[code];
      #pragma unroll
      for (int si = 0; si < 8; ++si) {
        float a = (si < 4) ? ac0[si & 3] : ac1[si & 3];
        float d = eec - 2.f * a;               // shifted by -||x||^2 (softmax-invariant)
        float mo = mS[si];
        float mn = fminf(mo, d);
        float E  = __expf(mn - fmaxf(mo, d));  // exp(-|d-mo|), one exp
        bool nw  = d < mo;
        float f  = nw ? E : 1.f;
        float e2 = nw ? 1.f : E;
        tS[si] = (tS[si] + (mn - mo) * sS[si]) * f + (mn - d) * e2;
        sS[si] = sS[si] * f + e2;
        kS[si] = nw ? code : kS[si];
        mS[si] = mn;
      }
    }
  }

  // ---- merge the 16 column-classes (butterfly over lane bits 0..3) ----
  #pragma unroll
  for (int off = 1; off <= 8; off <<= 1) {
    #pragma unroll
    for (int si = 0; si < 8; ++si) {
      float m2 = __shfl_xor(mS[si], off);
      float S2 = __shfl_xor(sS[si], off);
      float T2 = __shfl_xor(tS[si], off);
      int   k2 = __shfl_xor(kS[si], off);
      float mo = mS[si];
      float mn = fminf(mo, m2);
      float f1 = __expf(mn - mo);
      float f2 = __expf(mn - m2);
      tS[si] = (tS[si] + (mn - mo) * sS[si]) * f1 + (T2 + (mn - m2) * S2) * f2;
      sS[si] = sS[si] * f1 + S2 * f2;
      if (m2 < mo || (m2 == mo && k2 < kS[si])) kS[si] = k2;
      mS[si] = mn;
    }
  }

  // ---- finalize rows ----
  float cacc = 0.f, eacc = 0.f;
  #pragma unroll
  for (int si = 0; si < 8; ++si) {
    int rg = si >> 2, reg = si & 3;
    int row = wave * 32 + rg * 16 + quad * 4 + reg;
    if (col == 0) {
      float xx = xxs[row];
      int rn = n0 + row;
      float fk = (float)kS[si];
      out[IDX_OFF + rn] = fk;
      idxws[rn] = fk;
      ibkL[row] = kS[si];
      cacc += xx + mS[si];                    // d_min = ||x||^2 + shifted-min
      eacc += tS[si] / sS[si] - __logf(sS[si]);
    }
  }
  cacc += __shfl_xor(cacc, 16); cacc += __shfl_xor(cacc, 32);
  eacc += __shfl_xor(eacc, 16); eacc += __shfl_xor(eacc, 32);
  if (lane == 0) { red[wave] = cacc; red[4 + wave] = eacc; }
  __syncthreads();
  if (t == 0) {
    unsafeAtomicAdd(&sums[0], red[0] + red[1] + red[2] + red[3]);
    unsafeAtomicAdd(&sums[1], red[4] + red[5] + red[6] + red[7]);
  }

  // ---- fused quantized gather: 4 rounds of 32 rows through xs ----
  for (int r4 = 0; r4 < 4; ++r4) {
    __syncthreads();
    {
      const int rr = t & 31, c0 = (t >> 5) * 16;
      const int kq = ibkL[r4 * 32 + rr];
      const float* src = emb + (size_t)kq * 128 + c0;
      float4 v0 = *(const float4*)(src);
      float4 v1 = *(const float4*)(src + 4);
      float4 v2 = *(const float4*)(src + 8);
      float4 v3 = *(const float4*)(src + 12);
      float* dst = &xs[rr * 132 + c0];
      *(float4*)dst = v0; *(float4*)(dst + 4) = v1;
      *(float4*)(dst + 8) = v2; *(float4*)(dst + 12) = v3;
    }
    __syncthreads();
    {
      const int l7 = t & 7;
      #pragma unroll
      for (int pp = 0; pp < 4; ++pp) {
        int c = (t >> 3) + 32 * pp;
        float4 v;
        v.x = xs[(4 * l7 + 0) * 132 + c];
        v.y = xs[(4 * l7 + 1) * 132 + c];
        v.z = xs[(4 * l7 + 2) * 132 + c];
        v.w = xs[(4 * l7 + 3) * 132 + c];
        *(float4*)(out + ((size_t)b * 128 + c) * 32768 + s0 + r4 * 32 + 4 * l7) = v;
      }
    }
  }
}

// dw scatter: block = (row-split s, 8-channel slice ccB), grid = 16*S
__global__ __launch_bounds__(256) void scatter_kernel(
    const float* __restrict__ inputs, const float* __restrict__ idxws,
    float* __restrict__ partial, float* __restrict__ cpart, int S)
{
  __shared__ float acc[512 * 9];
  __shared__ float cnts[512];
  const int t = threadIdx.x;
  const int s = blockIdx.x >> 4, ccB = blockIdx.x & 15;
  const int R = 65536 / S;
  for (int m = t; m < 512 * 9; m += 256) acc[m] = 0.f;
  if (ccB == 0) for (int m = t; m < 512; m += 256) cnts[m] = 0.f;
  __syncthreads();
  const int l = t & 63, cg = t >> 6;
  for (int it = 0; it < R / 256; ++it) {
    int n = s * R + it * 256;
    int bb = n >> 15;
    int sp = (n & 32767) + 4 * l;
    float4 i4 = *(const float4*)(idxws + n + 4 * l);
    int k0 = (int)i4.x, k1 = (int)i4.y, k2 = (int)i4.z, k3 = (int)i4.w;
    #pragma unroll
    for (int ci = 0; ci < 2; ++ci) {
      int c = cg * 2 + ci;
      float4 x4 = *(const float4*)(inputs + ((size_t)bb * 128 + ccB * 8 + c) * 32768 + sp);
      atomicAdd(&acc[k0 * 9 + c], x4.x);
      atomicAdd(&acc[k1 * 9 + c], x4.y);
      atomicAdd(&acc[k2 * 9 + c], x4.z);
      atomicAdd(&acc[k3 * 9 + c], x4.w);
    }
    if (ccB == 0 && cg == 0) {
      atomicAdd(&cnts[k0], 1.f); atomicAdd(&cnts[k1], 1.f);
      atomicAdd(&cnts[k2], 1.f); atomicAdd(&cnts[k3], 1.f);
    }
  }
  __syncthreads();
  for (int m = t; m < 512 * 8; m += 256) {
    int k = m >> 3, c = m & 7;
    partial[(size_t)s * 65536 + k * 128 + ccB * 8 + c] = acc[k * 9 + c];
  }
  if (ccB == 0) for (int m = t; m < 512; m += 256) cpart[s * 512 + m] = cnts[m];
}

// finalize scalars
__global__ __launch_bounds__(512) void c1_kernel(const float* __restrict__ ecs,
    const float* __restrict__ cpart, const float* __restrict__ sums,
    float* __restrict__ invs, float* __restrict__ out, int S)
{
  __shared__ float sred[512];
  int t = threadIdx.x;
  float cnt = 0.f;
  for (int s = 0; s < S; ++s) cnt += cpart[s * 512 + t];
  float cn = 0.99f * ecs[t] + 0.01f * cnt;
  out[NCS_OFF + t] = cn;
  sred[t] = cn;
  __syncthreads();
  for (int o = 256; o; o >>= 1) {
    if (t < o) sred[t] += sred[t + o];
    __syncthreads();
  }
  float ntot = sred[0];
  float sm = (cn + 1e-5f) / (ntot + 0.00512f) * ntot;
  invs[t] = 1.f / sm;
  if (t == 0)
    out[LOSS_OFF] = 0.25f * sums[0] / 8388608.f - 0.01f * sums[1] / 65536.f;
}

// EMA weight update + normalized embedding (reduces S partials)
__global__ __launch_bounds__(256) void c2_kernel(const float* __restrict__ emaw,
    const float* __restrict__ partial, const float* __restrict__ invs,
    float* __restrict__ out, int S)
{
  int i = blockIdx.x * 256 + threadIdx.x;
  float dwv = 0.f;
  for (int s = 0; s < S; ++s) dwv += partial[(size_t)s * 65536 + i];
  float val = 0.99f * emaw[i] + 0.01f * dwv;
  out[EMAW_OFF + i] = val;
  out[EMB_OFF + i] = val * invs[i >> 7];
}

extern "C" void kernel_launch(void* const* d_in, const int* in_sizes, int n_in,
                              void* d_out, int out_size, void* d_ws, size_t ws_size,
                              hipStream_t stream) {
  const float* inputs = (const float*)d_in[0];
  const float* emb    = (const float*)d_in[1];
  const float* ecs    = (const float*)d_in[2];
  const float* emaw   = (const float*)d_in[3];
  float* out = (float*)d_out;
  float* wsf = (float*)d_ws;
  (void)in_sizes; (void)n_in; (void)out_size;

  size_t wsfl = ws_size / 4;
  int S = 32;
  while (S > 1 && (size_t)S * 66048 + 132128 > wsfl) S >>= 1;

  float* partial = wsf;
  float* cpart   = partial + (size_t)S * 65536;
  float* idxws   = cpart + (size_t)S * 512;
  float* sums    = idxws + 65536;
  float* eeg     = sums + 16;
  float* invs    = eeg + 512;
  unsigned short* ehig = (unsigned short*)(invs + 512);
  unsigned short* elog = ehig + 65536;

  hipMemsetAsync(sums, 0, 16 * sizeof(float), stream);
  prep_kernel   <<<256,    256, 0, stream>>>(emb, ehig, elog, eeg);
  dist_kernel   <<<512,    256, 0, stream>>>(inputs, emb, ehig, elog, eeg, out, idxws, sums);
  scatter_kernel<<<16 * S, 256, 0, stream>>>(inputs, idxws, partial, cpart, S);
  c1_kernel     <<<1,      512, 0, stream>>>(ecs, cpart, sums, invs, out, S);
  c2_kernel     <<<256,    256, 0, stream>>>(emaw, partial, invs, out, S);
}

// Round 6
// 211.635 us; speedup vs baseline: 1.7704x; 1.0102x over previous
//
#include <hip/hip_runtime.h>

// ---- output layout (floats) ----
#define LOSS_OFF  8388608
#define IDX_OFF   8388609
#define NCS_OFF   8454145
#define EMAW_OFF  8454657
#define EMB_OFF   8520193

typedef __attribute__((ext_vector_type(8))) short short8;
typedef __attribute__((ext_vector_type(4))) float f32x4;

__device__ __forceinline__ unsigned short bf16r(float x) {
  unsigned u = __float_as_uint(x);
  u += 0x7fff + ((u >> 16) & 1);
  return (unsigned short)(u >> 16);
}
__device__ __forceinline__ float bf16tof(unsigned short h) {
  return __uint_as_float(((unsigned)h) << 16);
}

// distances via split-bf16 MFMA + argmin + fused-entropy softmax + gather.
// 512 blocks x 256 thr; 128 rows/block, wave owns 32 rows (2 x 16-row groups).
// Codebook staged 32 codes/stage x 16 stages, double-buffered LDS, register
// prefetch issued before the single per-stage barrier. fp32 emb converted to
// bf16 hi/lo in-register (prep kernel eliminated); ||e||^2 via shuffle.
__global__ __attribute__((amdgpu_flat_work_group_size(256, 256),
                          amdgpu_waves_per_eu(2, 4)))
void dist_kernel(const float* __restrict__ inputs, const float* __restrict__ emb,
                 float* __restrict__ out, float* __restrict__ idxws,
                 float* __restrict__ sums)
{
  __shared__ __align__(16) short esm[2][2][32 * 136];  // [buf][hi/lo] 34.8 KB
  __shared__ float eeS[2][32];
  __shared__ float xxs[128];
  __shared__ int   ibkL[128];
  __shared__ float red[8];
  float* xs = (float*)&esm[0][0][0];          // [32][132] fp32, transient alias

  const int t = threadIdx.x, lane = t & 63, wave = t >> 6;
  const int n0 = blockIdx.x * 128;
  const int b = n0 >> 15, s0 = n0 & 32767;
  const int col = lane & 15, quad = lane >> 4;
  const int kk = t >> 3, c0 = (t & 7) * 16;   // staging coords

  short8 ahi[2][4], alo[2][4];
  // ---- x staging rounds: 32 rows/round; owning wave extracts frags + ||x||^2 ----
  for (int r4 = 0; r4 < 4; ++r4) {
    __syncthreads();
    {
      const int rr = t & 31, cc = (t >> 5) * 16;
      const float* src = inputs + (size_t)b * 128 * 32768 + s0 + r4 * 32 + rr;
      #pragma unroll
      for (int i = 0; i < 16; ++i)
        xs[rr * 132 + cc + i] = src[(size_t)(cc + i) * 32768];
    }
    __syncthreads();
    if (wave == r4) {
      #pragma unroll
      for (int rg = 0; rg < 2; ++rg) {
        float xacc = 0.f;
        const float* xr = &xs[(rg * 16 + col) * 132 + quad * 8];
        #pragma unroll
        for (int q = 0; q < 4; ++q) {
          float v[8];
          *(float4*)&v[0] = *(const float4*)(xr + q * 32);
          *(float4*)&v[4] = *(const float4*)(xr + q * 32 + 4);
          short8 h8, l8;
          #pragma unroll
          for (int j = 0; j < 8; ++j) {
            unsigned short hh = bf16r(v[j]);
            h8[j] = (short)hh;
            l8[j] = (short)bf16r(v[j] - bf16tof(hh));
            xacc += v[j] * v[j];
          }
          ahi[rg][q] = h8; alo[rg][q] = l8;
        }
        xacc += __shfl_xor(xacc, 16);
        xacc += __shfl_xor(xacc, 32);
        if (lane < 16) xxs[wave * 32 + rg * 16 + lane] = xacc;
      }
    }
  }
  __syncthreads();   // xs reads done before buf0 overwrite

  float mS[8], sS[8], tS[8]; int kS[8];
  #pragma unroll
  for (int i = 0; i < 8; ++i) { mS[i] = 1e30f; sS[i] = 0.f; tS[i] = 0.f; kS[i] = 0; }

  float4 pf0, pf1, pf2, pf3;
  // prologue: load + convert stage 0 into buf 0
  {
    const float* src = emb + (size_t)kk * 128 + c0;
    pf0 = ((const float4*)src)[0]; pf1 = ((const float4*)src)[1];
    pf2 = ((const float4*)src)[2]; pf3 = ((const float4*)src)[3];
    float v[16];
    *(float4*)&v[0] = pf0; *(float4*)&v[4] = pf1;
    *(float4*)&v[8] = pf2; *(float4*)&v[12] = pf3;
    short8 h0, h1, l0, l1; float sq = 0.f;
    #pragma unroll
    for (int j = 0; j < 8; ++j) {
      unsigned short hh = bf16r(v[j]);
      h0[j] = (short)hh; l0[j] = (short)bf16r(v[j] - bf16tof(hh));
      sq += v[j] * v[j];
      unsigned short hh2 = bf16r(v[8 + j]);
      h1[j] = (short)hh2; l1[j] = (short)bf16r(v[8 + j] - bf16tof(hh2));
      sq += v[8 + j] * v[8 + j];
    }
    *(short8*)&esm[0][0][kk * 136 + c0] = h0;
    *(short8*)&esm[0][0][kk * 136 + c0 + 8] = h1;
    *(short8*)&esm[0][1][kk * 136 + c0] = l0;
    *(short8*)&esm[0][1][kk * 136 + c0 + 8] = l1;
    sq += __shfl_xor(sq, 1); sq += __shfl_xor(sq, 2); sq += __shfl_xor(sq, 4);
    if ((t & 7) == 0) eeS[0][kk] = sq;
  }

  // ---- main loop: 16 stages x 32 codes, double-buffered, 1 barrier/stage ----
  for (int st = 0; st < 16; ++st) {
    const int pb = st & 1;
    if (st < 15) {            // prefetch stage st+1 (latency spans barrier+compute)
      const float* src = emb + (size_t)((st + 1) * 32 + kk) * 128 + c0;
      pf0 = ((const float4*)src)[0]; pf1 = ((const float4*)src)[1];
      pf2 = ((const float4*)src)[2]; pf3 = ((const float4*)src)[3];
    }
    __syncthreads();
    #pragma unroll
    for (int kt = 0; kt < 2; ++kt) {
      f32x4 ac0 = {0.f, 0.f, 0.f, 0.f}, ac1 = {0.f, 0.f, 0.f, 0.f};
      const int boff = (kt * 16 + col) * 136 + quad * 8;
      #pragma unroll
      for (int q = 0; q < 4; ++q) {
        short8 bh = *(const short8*)&esm[pb][0][boff + q * 32];
        short8 bl = *(const short8*)&esm[pb][1][boff + q * 32];
        ac0 = __builtin_amdgcn_mfma_f32_16x16x32_bf16(alo[0][q], bh, ac0, 0, 0, 0);
        ac1 = __builtin_amdgcn_mfma_f32_16x16x32_bf16(alo[1][q], bh, ac1, 0, 0, 0);
        ac0 = __builtin_amdgcn_mfma_f32_16x16x32_bf16(ahi[0][q], bl, ac0, 0, 0, 0);
        ac1 = __builtin_amdgcn_mfma_f32_16x16x32_bf16(ahi[1][q], bl, ac1, 0, 0, 0);
        ac0 = __builtin_amdgcn_mfma_f32_16x16x32_bf16(ahi[0][q], bh, ac0, 0, 0, 0);
        ac1 = __builtin_amdgcn_mfma_f32_16x16x32_bf16(ahi[1][q], bh, ac1, 0, 0, 0);
      }
      const int code = st * 32 + kt * 16 + col;
      const float eec = eeS[pb][kt * 16 + col];
      #pragma unroll
      for (int si = 0; si < 8; ++si) {
        float a = (si < 4) ? ac0[si & 3] : ac1[si & 3];
        float d = eec - 2.f * a;               // shifted by -||x||^2
        float mo = mS[si];
        float mn = fminf(mo, d);
        float E  = __expf(mn - fmaxf(mo, d));
        bool nw  = d < mo;
        float f  = nw ? E : 1.f;
        float e2 = nw ? 1.f : E;
        tS[si] = (tS[si] + (mn - mo) * sS[si]) * f + (mn - d) * e2;
        sS[si] = sS[si] * f + e2;
        kS[si] = nw ? code : kS[si];
        mS[si] = mn;
      }
    }
    if (st < 15) {            // convert + write stage st+1 into the other buffer
      const int nb = pb ^ 1;
      float v[16];
      *(float4*)&v[0] = pf0; *(float4*)&v[4] = pf1;
      *(float4*)&v[8] = pf2; *(float4*)&v[12] = pf3;
      short8 h0, h1, l0, l1; float sq = 0.f;
      #pragma unroll
      for (int j = 0; j < 8; ++j) {
        unsigned short hh = bf16r(v[j]);
        h0[j] = (short)hh; l0[j] = (short)bf16r(v[j] - bf16tof(hh));
        sq += v[j] * v[j];
        unsigned short hh2 = bf16r(v[8 + j]);
        h1[j] = (short)hh2; l1[j] = (short)bf16r(v[8 + j] - bf16tof(hh2));
        sq += v[8 + j] * v[8 + j];
      }
      *(short8*)&esm[nb][0][kk * 136 + c0] = h0;
      *(short8*)&esm[nb][0][kk * 136 + c0 + 8] = h1;
      *(short8*)&esm[nb][1][kk * 136 + c0] = l0;
      *(short8*)&esm[nb][1][kk * 136 + c0 + 8] = l1;
      sq += __shfl_xor(sq, 1); sq += __shfl_xor(sq, 2); sq += __shfl_xor(sq, 4);
      if ((t & 7) == 0) eeS[nb][kk] = sq;
    }
  }

  // ---- merge the 16 column-classes (butterfly over lane bits 0..3) ----
  #pragma unroll
  for (int off = 1; off <= 8; off <<= 1) {
    #pragma unroll
    for (int si = 0; si < 8; ++si) {
      float m2 = __shfl_xor(mS[si], off);
      float S2 = __shfl_xor(sS[si], off);
      float T2 = __shfl_xor(tS[si], off);
      int   k2 = __shfl_xor(kS[si], off);
      float mo = mS[si];
      float mn = fminf(mo, m2);
      float f1 = __expf(mn - mo);
      float f2 = __expf(mn - m2);
      tS[si] = (tS[si] + (mn - mo) * sS[si]) * f1 + (T2 + (mn - m2) * S2) * f2;
      sS[si] = sS[si] * f1 + S2 * f2;
      if (m2 < mo || (m2 == mo && k2 < kS[si])) kS[si] = k2;
      mS[si] = mn;
    }
  }

  // ---- finalize rows ----
  float cacc = 0.f, eacc = 0.f;
  #pragma unroll
  for (int si = 0; si < 8; ++si) {
    int rg = si >> 2, reg = si & 3;
    int row = wave * 32 + rg * 16 + quad * 4 + reg;
    if (col == 0) {
      float xx = xxs[row];
      int rn = n0 + row;
      float fk = (float)kS[si];
      out[IDX_OFF + rn] = fk;
      idxws[rn] = fk;
      ibkL[row] = kS[si];
      cacc += xx + mS[si];
      eacc += tS[si] / sS[si] - __logf(sS[si]);
    }
  }
  cacc += __shfl_xor(cacc, 16); cacc += __shfl_xor(cacc, 32);
  eacc += __shfl_xor(eacc, 16); eacc += __shfl_xor(eacc, 32);
  if (lane == 0) { red[wave] = cacc; red[4 + wave] = eacc; }
  __syncthreads();
  if (t == 0) {
    unsafeAtomicAdd(&sums[0], red[0] + red[1] + red[2] + red[3]);
    unsafeAtomicAdd(&sums[1], red[4] + red[5] + red[6] + red[7]);
  }

  // ---- fused quantized gather: 4 rounds of 32 rows through xs ----
  for (int r4 = 0; r4 < 4; ++r4) {
    __syncthreads();
    {
      const int rr = t & 31, cc = (t >> 5) * 16;
      const int kq = ibkL[r4 * 32 + rr];
      const float* src = emb + (size_t)kq * 128 + cc;
      float4 v0 = *(const float4*)(src);
      float4 v1 = *(const float4*)(src + 4);
      float4 v2 = *(const float4*)(src + 8);
      float4 v3 = *(const float4*)(src + 12);
      float* dst = &xs[rr * 132 + cc];
      *(float4*)dst = v0; *(float4*)(dst + 4) = v1;
      *(float4*)(dst + 8) = v2; *(float4*)(dst + 12) = v3;
    }
    __syncthreads();
    {
      const int l7 = t & 7;
      #pragma unroll
      for (int pp = 0; pp < 4; ++pp) {
        int c = (t >> 3) + 32 * pp;
        float4 v;
        v.x = xs[(4 * l7 + 0) * 132 + c];
        v.y = xs[(4 * l7 + 1) * 132 + c];
        v.z = xs[(4 * l7 + 2) * 132 + c];
        v.w = xs[(4 * l7 + 3) * 132 + c];
        *(float4*)(out + ((size_t)b * 128 + c) * 32768 + s0 + r4 * 32 + 4 * l7) = v;
      }
    }
  }
}

// dw scatter: block = (row-split s, 8-channel slice ccB), grid = 16*S
__global__ __launch_bounds__(256) void scatter_kernel(
    const float* __restrict__ inputs, const float* __restrict__ idxws,
    float* __restrict__ partial, float* __restrict__ cpart, int S)
{
  __shared__ float acc[512 * 9];
  __shared__ float cnts[512];
  const int t = threadIdx.x;
  const int s = blockIdx.x >> 4, ccB = blockIdx.x & 15;
  const int R = 65536 / S;
  for (int m = t; m < 512 * 9; m += 256) acc[m] = 0.f;
  if (ccB == 0) for (int m = t; m < 512; m += 256) cnts[m] = 0.f;
  __syncthreads();
  const int l = t & 63, cg = t >> 6;
  for (int it = 0; it < R / 256; ++it) {
    int n = s * R + it * 256;
    int bb = n >> 15;
    int sp = (n & 32767) + 4 * l;
    float4 i4 = *(const float4*)(idxws + n + 4 * l);
    int k0 = (int)i4.x, k1 = (int)i4.y, k2 = (int)i4.z, k3 = (int)i4.w;
    #pragma unroll
    for (int ci = 0; ci < 2; ++ci) {
      int c = cg * 2 + ci;
      float4 x4 = *(const float4*)(inputs + ((size_t)bb * 128 + ccB * 8 + c) * 32768 + sp);
      atomicAdd(&acc[k0 * 9 + c], x4.x);
      atomicAdd(&acc[k1 * 9 + c], x4.y);
      atomicAdd(&acc[k2 * 9 + c], x4.z);
      atomicAdd(&acc[k3 * 9 + c], x4.w);
    }
    if (ccB == 0 && cg == 0) {
      atomicAdd(&cnts[k0], 1.f); atomicAdd(&cnts[k1], 1.f);
      atomicAdd(&cnts[k2], 1.f); atomicAdd(&cnts[k3], 1.f);
    }
  }
  __syncthreads();
  for (int m = t; m < 512 * 8; m += 256) {
    int k = m >> 3, c = m & 7;
    partial[(size_t)s * 65536 + k * 128 + ccB * 8 + c] = acc[k * 9 + c];
  }
  if (ccB == 0) for (int m = t; m < 512; m += 256) cpart[s * 512 + m] = cnts[m];
}

// fused finalize: counts reduce + smoothed + loss + EMA update + embedding
// Each block redundantly reduces counts -> ntot; block 0 writes NCS + loss.
__global__ __launch_bounds__(256) void fin_kernel(const float* __restrict__ ecs,
    const float* __restrict__ emaw, const float* __restrict__ partial,
    const float* __restrict__ cpart, const float* __restrict__ sums,
    float* __restrict__ out, int S)
{
  __shared__ float cn[512];
  __shared__ float rsum[256];
  const int t = threadIdx.x;
  float local = 0.f;
  for (int k = t; k < 512; k += 256) {
    float c = 0.f;
    for (int s = 0; s < S; ++s) c += cpart[s * 512 + k];
    float v = 0.99f * ecs[k] + 0.01f * c;
    cn[k] = v; local += v;
  }
  rsum[t] = local;
  __syncthreads();
  for (int o = 128; o; o >>= 1) {
    if (t < o) rsum[t] += rsum[t + o];
    __syncthreads();
  }
  const float ntot = rsum[0];
  if (blockIdx.x == 0) {
    for (int k = t; k < 512; k += 256) out[NCS_OFF + k] = cn[k];
    if (t == 0)
      out[LOSS_OFF] = 0.25f * sums[0] / 8388608.f - 0.01f * sums[1] / 65536.f;
  }
  const int i = blockIdx.x * 256 + t;
  float dwv = 0.f;
  for (int s = 0; s < S; ++s) dwv += partial[(size_t)s * 65536 + i];
  float val = 0.99f * emaw[i] + 0.01f * dwv;
  const int k = i >> 7;
  float sm = (cn[k] + 1e-5f) / (ntot + 0.00512f) * ntot;
  out[EMAW_OFF + i] = val;
  out[EMB_OFF + i] = val / sm;
}

extern "C" void kernel_launch(void* const* d_in, const int* in_sizes, int n_in,
                              void* d_out, int out_size, void* d_ws, size_t ws_size,
                              hipStream_t stream) {
  const float* inputs = (const float*)d_in[0];
  const float* emb    = (const float*)d_in[1];
  const float* ecs    = (const float*)d_in[2];
  const float* emaw   = (const float*)d_in[3];
  float* out = (float*)d_out;
  float* wsf = (float*)d_ws;
  (void)in_sizes; (void)n_in; (void)out_size;

  size_t wsfl = ws_size / 4;
  int S = 16;
  while (S > 1 && (size_t)S * 66048 + 65552 > wsfl) S >>= 1;

  float* partial = wsf;
  float* cpart   = partial + (size_t)S * 65536;
  float* idxws   = cpart + (size_t)S * 512;
  float* sums    = idxws + 65536;

  hipMemsetAsync(sums, 0, 16 * sizeof(float), stream);
  dist_kernel   <<<512,    256, 0, stream>>>(inputs, emb, out, idxws, sums);
  scatter_kernel<<<16 * S, 256, 0, stream>>>(inputs, idxws, partial, cpart, S);
  fin_kernel    <<<256,    256, 0, stream>>>(ecs, emaw, partial, cpart, sums, out, S);
}

// Round 7
// 199.591 us; speedup vs baseline: 1.8772x; 1.0603x over previous
//
#include <hip/hip_runtime.h>

// ---- output layout (floats) ----
#define LOSS_OFF  8388608
#define IDX_OFF   8388609
#define NCS_OFF   8454145
#define EMAW_OFF  8454657
#define EMB_OFF   8520193

typedef __attribute__((ext_vector_type(8))) short short8;
typedef __attribute__((ext_vector_type(4))) float f32x4;

#define LOG2E 1.4426950408889634f
#define N2L2E -2.8853900817779268f   // -2*log2(e)
#define LN2   0.6931471805599453f
#define NSPLIT 32                     // scatter row-splits (partials live in d_out)

__device__ __forceinline__ unsigned short bf16r(float x) {
  unsigned u = __float_as_uint(x);
  u += 0x7fff + ((u >> 16) & 1);
  return (unsigned short)(u >> 16);
}
__device__ __forceinline__ float bf16tof(unsigned short h) {
  return __uint_as_float(((unsigned)h) << 16);
}

// codebook prep: bf16 hi/lo split + log2e*||e_k||^2. grid 256 (2 codes/block)
__global__ __launch_bounds__(256) void prep_kernel(const float* __restrict__ emb,
    unsigned short* __restrict__ ehig, unsigned short* __restrict__ elog,
    float* __restrict__ eeg)
{
  __shared__ float r1[256];
  const int t = threadIdx.x;
  const int k = blockIdx.x * 2 + (t >> 7);
  const int c = t & 127;
  float x = emb[k * 128 + c];
  unsigned short hh = bf16r(x);
  ehig[k * 128 + c] = hh;
  elog[k * 128 + c] = bf16r(x - bf16tof(hh));
  r1[t] = x * x;
  __syncthreads();
  #pragma unroll
  for (int off = 64; off; off >>= 1) {
    if ((t & 127) < off) r1[t] += r1[t + off];
    __syncthreads();
  }
  if ((t & 127) == 0) eeg[k] = LOG2E * r1[t];
}

// distances via split-bf16 MFMA + argmin + base-2 fused-entropy softmax.
// 1024 blocks x 256 thr; 64 rows/block, wave owns 16 rows (one 16x16 group).
// Codebook staged 32 codes/stage x 16 stages, double-buffered, 1 barrier/stage,
// register prefetch of stage st+2 issued right after buffer write.
__global__ __attribute__((amdgpu_flat_work_group_size(256, 256),
                          amdgpu_waves_per_eu(2, 4)))
void dist_kernel(const float* __restrict__ inputs,
                 const unsigned short* __restrict__ ehig,
                 const unsigned short* __restrict__ elog,
                 const float* __restrict__ eeg,
                 float* __restrict__ out, float* __restrict__ idxws,
                 float* __restrict__ sums)
{
  __shared__ __align__(16) short esm[2][2][32 * 136];  // [buf][hi/lo] 34 KB
  __shared__ float eeL[512];
  __shared__ float xxs[64];
  __shared__ float red[8];
  float* xs = (float*)&esm[0][0][0];          // [32][132] fp32, transient alias

  const int t = threadIdx.x, lane = t & 63, wave = t >> 6;
  const int n0 = blockIdx.x * 64;
  const int b = n0 >> 15, s0 = n0 & 32767;
  const int col = lane & 15, quad = lane >> 4;
  const int kk = t >> 3, c0s = (t & 7) * 16;  // staging coords

  eeL[t] = eeg[t]; eeL[256 + t] = eeg[256 + t];

  short8 ahi[4], alo[4];
  // ---- x staging: 2 rounds of 32 rows; owning waves extract frags + ||x||^2 ----
  for (int r4 = 0; r4 < 2; ++r4) {
    __syncthreads();
    {
      const int rr = t & 31, cc = (t >> 5) * 16;
      const float* src = inputs + (size_t)b * 128 * 32768 + s0 + r4 * 32 + rr;
      #pragma unroll
      for (int i = 0; i < 16; ++i)
        xs[rr * 132 + cc + i] = src[(size_t)(cc + i) * 32768];
    }
    __syncthreads();
    if ((wave >> 1) == r4) {
      float xacc = 0.f;
      const float* xr = &xs[((wave & 1) * 16 + col) * 132 + quad * 8];
      #pragma unroll
      for (int q = 0; q < 4; ++q) {
        float v[8];
        *(float4*)&v[0] = *(const float4*)(xr + q * 32);
        *(float4*)&v[4] = *(const float4*)(xr + q * 32 + 4);
        short8 h8, l8;
        #pragma unroll
        for (int j = 0; j < 8; ++j) {
          unsigned short hh = bf16r(v[j]);
          h8[j] = (short)hh;
          l8[j] = (short)bf16r(v[j] - bf16tof(hh));
          xacc += v[j] * v[j];
        }
        ahi[q] = h8; alo[q] = l8;
      }
      xacc += __shfl_xor(xacc, 16);
      xacc += __shfl_xor(xacc, 32);
      if (quad == 0) xxs[wave * 16 + col] = xacc;
    }
  }
  __syncthreads();   // xs reads done before buf0 overwrite

  // prologue: stage 0 -> buf0; prefetch stage 1 into regs
  uint4 ph0, ph1, pl0, pl1;
  {
    const size_t go = (size_t)kk * 128 + c0s;
    ph0 = ((const uint4*)(ehig + go))[0]; ph1 = ((const uint4*)(ehig + go))[1];
    pl0 = ((const uint4*)(elog + go))[0]; pl1 = ((const uint4*)(elog + go))[1];
  }
  *(uint4*)&esm[0][0][kk * 136 + c0s] = ph0;
  *(uint4*)&esm[0][0][kk * 136 + c0s + 8] = ph1;
  *(uint4*)&esm[0][1][kk * 136 + c0s] = pl0;
  *(uint4*)&esm[0][1][kk * 136 + c0s + 8] = pl1;
  {
    const size_t go = (size_t)(32 + kk) * 128 + c0s;
    ph0 = ((const uint4*)(ehig + go))[0]; ph1 = ((const uint4*)(ehig + go))[1];
    pl0 = ((const uint4*)(elog + go))[0]; pl1 = ((const uint4*)(elog + go))[1];
  }

  float mS[4], sS[4], tS[4]; int kS[4];
  #pragma unroll
  for (int i = 0; i < 4; ++i) { mS[i] = 1e30f; sS[i] = 0.f; tS[i] = 0.f; kS[i] = 0; }

  // ---- main loop: 16 stages x 32 codes, 1 barrier/stage ----
  for (int st = 0; st < 16; ++st) {
    const int pb = st & 1;
    __syncthreads();
    #pragma unroll
    for (int kt = 0; kt < 2; ++kt) {
      f32x4 ac = {0.f, 0.f, 0.f, 0.f};
      const int boff = (kt * 16 + col) * 136 + quad * 8;
      #pragma unroll
      for (int q = 0; q < 4; ++q) {
        short8 bh = *(const short8*)&esm[pb][0][boff + q * 32];
        short8 bl = *(const short8*)&esm[pb][1][boff + q * 32];
        ac = __builtin_amdgcn_mfma_f32_16x16x32_bf16(alo[q], bh, ac, 0, 0, 0);
        ac = __builtin_amdgcn_mfma_f32_16x16x32_bf16(ahi[q], bl, ac, 0, 0, 0);
        ac = __builtin_amdgcn_mfma_f32_16x16x32_bf16(ahi[q], bh, ac, 0, 0, 0);
      }
      const int code = st * 32 + kt * 16 + col;
      const float eec2 = eeL[code];
      #pragma unroll
      for (int si = 0; si < 4; ++si) {
        float d  = fmaf(ac[si], N2L2E, eec2);   // log2e * (||e||^2 - 2<x,e>)
        float mo = mS[si];
        float mn = fminf(mo, d);
        float mx = fmaxf(mo, d);
        float E  = __builtin_amdgcn_exp2f(mn - mx);
        bool nw  = d < mo;
        float f  = nw ? E : 1.f;
        float e2 = nw ? 1.f : E;
        tS[si] = (tS[si] + (mn - mo) * sS[si]) * f + (mn - d) * e2;
        sS[si] = sS[si] * f + e2;
        kS[si] = nw ? code : kS[si];
        mS[si] = mn;
      }
    }
    if (st < 15) {      // write stage st+1 into other buffer, prefetch st+2
      const int nb = pb ^ 1;
      *(uint4*)&esm[nb][0][kk * 136 + c0s] = ph0;
      *(uint4*)&esm[nb][0][kk * 136 + c0s + 8] = ph1;
      *(uint4*)&esm[nb][1][kk * 136 + c0s] = pl0;
      *(uint4*)&esm[nb][1][kk * 136 + c0s + 8] = pl1;
      if (st < 14) {
        const size_t go = (size_t)((st + 2) * 32 + kk) * 128 + c0s;
        ph0 = ((const uint4*)(ehig + go))[0]; ph1 = ((const uint4*)(ehig + go))[1];
        pl0 = ((const uint4*)(elog + go))[0]; pl1 = ((const uint4*)(elog + go))[1];
      }
    }
  }

  // ---- merge the 16 column-classes (butterfly over lane bits 0..3) ----
  #pragma unroll
  for (int off = 1; off <= 8; off <<= 1) {
    #pragma unroll
    for (int si = 0; si < 4; ++si) {
      float m2 = __shfl_xor(mS[si], off);
      float S2 = __shfl_xor(sS[si], off);
      float T2 = __shfl_xor(tS[si], off);
      int   k2 = __shfl_xor(kS[si], off);
      float mo = mS[si];
      float mn = fminf(mo, m2);
      float f1 = __builtin_amdgcn_exp2f(mn - mo);
      float f2 = __builtin_amdgcn_exp2f(mn - m2);
      tS[si] = (tS[si] + (mn - mo) * sS[si]) * f1 + (T2 + (mn - m2) * S2) * f2;
      sS[si] = sS[si] * f1 + S2 * f2;
      if (m2 < mo || (m2 == mo && k2 < kS[si])) kS[si] = k2;
      mS[si] = mn;
    }
  }

  // ---- finalize rows ----
  float cacc = 0.f, eacc = 0.f;
  if (col == 0) {
    #pragma unroll
    for (int si = 0; si < 4; ++si) {
      int row = wave * 16 + quad * 4 + si;
      int rn = n0 + row;
      float fk = (float)kS[si];
      out[IDX_OFF + rn] = fk;
      idxws[rn] = fk;
      cacc += xxs[row] + mS[si] * LN2;          // d_min = ||x||^2 + ln2*shifted
      eacc += LN2 * (tS[si] / sS[si] - __builtin_amdgcn_logf(sS[si]));
    }
  }
  cacc += __shfl_xor(cacc, 16); cacc += __shfl_xor(cacc, 32);
  eacc += __shfl_xor(eacc, 16); eacc += __shfl_xor(eacc, 32);
  if (lane == 0) { red[wave] = cacc; red[4 + wave] = eacc; }
  __syncthreads();
  if (t == 0) {
    unsafeAtomicAdd(&sums[0], red[0] + red[1] + red[2] + red[3]);
    unsafeAtomicAdd(&sums[1], red[4] + red[5] + red[6] + red[7]);
  }
}

// dw scatter: block = (row-split s, 8-channel slice ccB), grid = 16*NSPLIT.
// Partials written into d_out's quantized region (overwritten later by gather).
__global__ __launch_bounds__(256) void scatter_kernel(
    const float* __restrict__ inputs, const float* __restrict__ idxws,
    float* partial, float* __restrict__ cpart)
{
  __shared__ float acc[512 * 9];
  __shared__ float cnts[512];
  const int t = threadIdx.x;
  const int s = blockIdx.x >> 4, ccB = blockIdx.x & 15;
  const int R = 65536 / NSPLIT;
  for (int m = t; m < 512 * 9; m += 256) acc[m] = 0.f;
  if (ccB == 0) for (int m = t; m < 512; m += 256) cnts[m] = 0.f;
  __syncthreads();
  const int l = t & 63, cg = t >> 6;
  for (int it = 0; it < R / 256; ++it) {
    int n = s * R + it * 256;
    int bb = n >> 15;
    int sp = (n & 32767) + 4 * l;
    float4 i4 = *(const float4*)(idxws + n + 4 * l);
    int k0 = (int)i4.x, k1 = (int)i4.y, k2 = (int)i4.z, k3 = (int)i4.w;
    #pragma unroll
    for (int ci = 0; ci < 2; ++ci) {
      int c = cg * 2 + ci;
      float4 x4 = *(const float4*)(inputs + ((size_t)bb * 128 + ccB * 8 + c) * 32768 + sp);
      atomicAdd(&acc[k0 * 9 + c], x4.x);
      atomicAdd(&acc[k1 * 9 + c], x4.y);
      atomicAdd(&acc[k2 * 9 + c], x4.z);
      atomicAdd(&acc[k3 * 9 + c], x4.w);
    }
    if (ccB == 0 && cg == 0) {
      atomicAdd(&cnts[k0], 1.f); atomicAdd(&cnts[k1], 1.f);
      atomicAdd(&cnts[k2], 1.f); atomicAdd(&cnts[k3], 1.f);
    }
  }
  __syncthreads();
  for (int m = t; m < 512 * 8; m += 256) {
    int k = m >> 3, c = m & 7;
    partial[(size_t)s * 65536 + k * 128 + ccB * 8 + c] = acc[k * 9 + c];
  }
  if (ccB == 0) for (int m = t; m < 512; m += 256) cpart[s * 512 + m] = cnts[m];
}

// fused finalize: counts reduce + smoothed + loss + EMA update + embedding.
// partial aliases out's quantized region (read-only here) — no __restrict__.
__global__ __launch_bounds__(256) void fin_kernel(const float* __restrict__ ecs,
    const float* __restrict__ emaw, const float* partial,
    const float* __restrict__ cpart, const float* __restrict__ sums,
    float* out)
{
  __shared__ float cn[512];
  __shared__ float rsum[256];
  const int t = threadIdx.x;
  float local = 0.f;
  for (int k = t; k < 512; k += 256) {
    float c = 0.f;
    for (int s = 0; s < NSPLIT; ++s) c += cpart[s * 512 + k];
    float v = 0.99f * ecs[k] + 0.01f * c;
    cn[k] = v; local += v;
  }
  rsum[t] = local;
  __syncthreads();
  for (int o = 128; o; o >>= 1) {
    if (t < o) rsum[t] += rsum[t + o];
    __syncthreads();
  }
  const float ntot = rsum[0];
  if (blockIdx.x == 0) {
    for (int k = t; k < 512; k += 256) out[NCS_OFF + k] = cn[k];
    if (t == 0)
      out[LOSS_OFF] = 0.25f * sums[0] / 8388608.f - 0.01f * sums[1] / 65536.f;
  }
  const int i = blockIdx.x * 256 + t;
  float dwv = 0.f;
  for (int s = 0; s < NSPLIT; ++s) dwv += partial[(size_t)s * 65536 + i];
  float val = 0.99f * emaw[i] + 0.01f * dwv;
  const int k = i >> 7;
  float sm = (cn[k] + 1e-5f) / (ntot + 0.00512f) * ntot;
  out[EMAW_OFF + i] = val;
  out[EMB_OFF + i] = val / sm;
}

// quantized gather: 64 spatial x 128 c per block, LDS transpose, coalesced writes.
// Runs LAST: overwrites the quantized region used as partial scratch.
__global__ __launch_bounds__(256) void gather_kernel(const float* __restrict__ emb,
    const float* __restrict__ idxws, float* __restrict__ out)
{
  __shared__ float eq[128 * 64];   // [c][s]
  const int t  = threadIdx.x;
  const int n0 = blockIdx.x * 64;
  const int b  = n0 >> 15;
  const int s0 = n0 & 32767;
  {
    const int r  = t >> 2;
    const int qq = t & 3;
    const int kidx = (int)idxws[n0 + r];
    const float* src = emb + (size_t)kidx * 128;
    #pragma unroll
    for (int i = 0; i < 8; ++i) {
      int g = qq + 4 * i;
      float4 v = *(const float4*)(src + g * 4);
      float* dst = &eq[(g * 4) * 64 + r];
      dst[0] = v.x; dst[64] = v.y; dst[128] = v.z; dst[192] = v.w;
    }
  }
  __syncthreads();
  {
    const int sl = (t & 15) * 4;
    const int cb = t >> 4;
    #pragma unroll
    for (int j = 0; j < 8; ++j) {
      int c = cb + 16 * j;
      float4 v = *(const float4*)&eq[c * 64 + sl];
      *(float4*)(out + ((size_t)b * 128 + c) * 32768 + s0 + sl) = v;
    }
  }
}

extern "C" void kernel_launch(void* const* d_in, const int* in_sizes, int n_in,
                              void* d_out, int out_size, void* d_ws, size_t ws_size,
                              hipStream_t stream) {
  const float* inputs = (const float*)d_in[0];
  const float* emb    = (const float*)d_in[1];
  const float* ecs    = (const float*)d_in[2];
  const float* emaw   = (const float*)d_in[3];
  float* out = (float*)d_out;
  float* wsf = (float*)d_ws;
  (void)in_sizes; (void)n_in; (void)out_size; (void)ws_size;

  // ws layout (floats): idxws 65536 | sums 16 | eeg 512 | ehig 32768 | elog 32768
  //                     | cpart 16384  -> total 147,984 floats (592 KB)
  float* idxws = wsf;
  float* sums  = wsf + 65536;
  float* eeg   = wsf + 65552;
  unsigned short* ehig = (unsigned short*)(wsf + 66064);
  unsigned short* elog = ehig + 65536;
  float* cpart = (float*)(elog + 65536);

  hipMemsetAsync(sums, 0, 16 * sizeof(float), stream);
  prep_kernel   <<<256,        256, 0, stream>>>(emb, ehig, elog, eeg);
  dist_kernel   <<<1024,       256, 0, stream>>>(inputs, ehig, elog, eeg, out, idxws, sums);
  scatter_kernel<<<16 * NSPLIT,256, 0, stream>>>(inputs, idxws, out, cpart);
  fin_kernel    <<<256,        256, 0, stream>>>(ecs, emaw, out, cpart, sums, out);
  gather_kernel <<<1024,       256, 0, stream>>>(emb, idxws, out);
}